// Round 3
// baseline (166.341 us; speedup 1.0000x reference)
//
#include <hip/hip_runtime.h>

#define VOCAB 100000
#define DIM 128
#define BATCH 262144
#define NEG 5

__device__ __forceinline__ float softplus_stable(float x) {
    // log(1 + exp(x)) computed stably
    return log1pf(__expf(-fabsf(x))) + fmaxf(x, 0.0f);
}

__global__ void ns_init_kernel(float* acc) {
    acc[0] = 0.0f;
    acc[1] = 0.0f;
}

__global__ __launch_bounds__(256) void ns_loss_kernel(
    const int* __restrict__ tgt,
    const int* __restrict__ ctx,
    const int* __restrict__ negw,
    const float* __restrict__ iemb,
    const float* __restrict__ oemb,
    float* __restrict__ acc)
{
    const int tid = threadIdx.x;
    const int r = tid & 31;                 // lane within half-wave
    const int hw_in_block = tid >> 5;       // 8 half-waves per 256-thread block
    const int hw_global = blockIdx.x * 8 + hw_in_block;
    const int hw_total = gridDim.x * 8;

    float pos_acc = 0.0f, neg_acc = 0.0f;

    for (int e = hw_global; e < BATCH; e += hw_total) {
        const int tw = tgt[e];
        const int cw = ctx[e];

        // one 512B row per half-wave: lane r holds elements [4r, 4r+4)
        const float4 t4 = *reinterpret_cast<const float4*>(iemb + (size_t)tw * DIM + r * 4);
        const float4 c4 = *reinterpret_cast<const float4*>(oemb + (size_t)cw * DIM + r * 4);

        float dp = t4.x * c4.x + t4.y * c4.y + t4.z * c4.z + t4.w * c4.w;

        float dn[NEG];
        #pragma unroll
        for (int j = 0; j < NEG; ++j) {
            const int nw = negw[e * NEG + j];
            const float4 n4 = *reinterpret_cast<const float4*>(oemb + (size_t)nw * DIM + r * 4);
            dn[j] = t4.x * n4.x + t4.y * n4.y + t4.z * n4.z + t4.w * n4.w;
        }

        // butterfly reduce across the 32 lanes of the half-wave
        #pragma unroll
        for (int m = 16; m >= 1; m >>= 1) {
            dp += __shfl_xor(dp, m, 64);
            #pragma unroll
            for (int j = 0; j < NEG; ++j) dn[j] += __shfl_xor(dn[j], m, 64);
        }

        if (r == 0) {
            // positive_loss term: -log_sigmoid(dp) = softplus(-dp)
            pos_acc += softplus_stable(-dp);
            // negative_loss term: -log_sigmoid(-dn) = softplus(dn)
            float s = 0.0f;
            #pragma unroll
            for (int j = 0; j < NEG; ++j) s += softplus_stable(dn[j]);
            neg_acc += s;
        }
    }

    // block reduction over 256 threads (only r==0 threads hold nonzero)
    __shared__ float sp[256];
    __shared__ float sn[256];
    sp[tid] = pos_acc;
    sn[tid] = neg_acc;
    __syncthreads();
    #pragma unroll
    for (int s = 128; s > 0; s >>= 1) {
        if (tid < s) {
            sp[tid] += sp[tid + s];
            sn[tid] += sn[tid + s];
        }
        __syncthreads();
    }
    if (tid == 0) {
        atomicAdd(&acc[0], sp[0]);
        atomicAdd(&acc[1], sn[0]);
    }
}

__global__ void ns_finalize_kernel(const float* __restrict__ acc, float* __restrict__ out) {
    out[0] = acc[0] * (1.0f / (float)BATCH);
    out[1] = acc[1] * (1.0f / ((float)BATCH * (float)NEG));
}

extern "C" void kernel_launch(void* const* d_in, const int* in_sizes, int n_in,
                              void* d_out, int out_size, void* d_ws, size_t ws_size,
                              hipStream_t stream) {
    const int*   tgt  = (const int*)d_in[0];
    const int*   ctx  = (const int*)d_in[1];
    const int*   negw = (const int*)d_in[2];
    const float* iemb = (const float*)d_in[3];
    const float* oemb = (const float*)d_in[4];
    float* out = (float*)d_out;
    float* acc = (float*)d_ws;

    ns_init_kernel<<<1, 1, 0, stream>>>(acc);
    ns_loss_kernel<<<2048, 256, 0, stream>>>(tgt, ctx, negw, iemb, oemb, acc);
    ns_finalize_kernel<<<1, 1, 0, stream>>>(acc, out);
}

// Round 4
// 151.767 us; speedup vs baseline: 1.0960x; 1.0960x over previous
//
#include <hip/hip_runtime.h>

#define VOCAB 100000
#define DIM 128
#define BATCH 262144
#define NEG 5

// log(1 + exp(x)), branchless-stable. For this problem |x| <~ 0.02 so
// z = exp(-|x|) is in [0.98, 1]: logf(1+z) has no cancellation issue
// (log1pf is only needed when z -> 0). __expf/__logf -> v_exp_f32/v_log_f32.
__device__ __forceinline__ float softplus_fast(float x) {
    return fmaxf(x, 0.0f) + __logf(1.0f + __expf(-fabsf(x)));
}

__device__ __forceinline__ float dot4(const float4 a, const float4 b) {
    return a.x * b.x + a.y * b.y + a.z * b.z + a.w * b.w;
}

__global__ void ns_init_kernel(float* acc) {
    acc[0] = 0.0f;
    acc[1] = 0.0f;
}

__global__ __launch_bounds__(256) void ns_loss_kernel(
    const int* __restrict__ tgt,
    const int* __restrict__ ctx,
    const int* __restrict__ negw,
    const float* __restrict__ iemb,
    const float* __restrict__ oemb,
    float* __restrict__ acc)
{
    const int tid = threadIdx.x;
    const int r   = tid & 7;        // lane within 8-lane group; covers dims [16r, 16r+16)
    const int grp = tid >> 3;       // 32 groups per 256-thread block
    const int e0  = blockIdx.x * 32 + grp;
    const int estride = gridDim.x * 32;

    float pos_acc = 0.0f, neg_acc = 0.0f;

    for (int e = e0; e < BATCH; e += estride) {
        const int tw = tgt[e];
        const int cw = ctx[e];

        // each 8-lane group reads one 512B row as 4x contiguous 128B segments
        const float4* tp = reinterpret_cast<const float4*>(iemb + (size_t)tw * DIM) + r * 4;
        const float4 t0 = tp[0], t1 = tp[1], t2 = tp[2], t3 = tp[3];

        const float4* cp = reinterpret_cast<const float4*>(oemb + (size_t)cw * DIM) + r * 4;
        float dp = dot4(t0, cp[0]) + dot4(t1, cp[1]) + dot4(t2, cp[2]) + dot4(t3, cp[3]);

        float dn[NEG];
        #pragma unroll
        for (int j = 0; j < NEG; ++j) {
            const int nw = negw[e * NEG + j];
            const float4* np_ = reinterpret_cast<const float4*>(oemb + (size_t)nw * DIM) + r * 4;
            dn[j] = dot4(t0, np_[0]) + dot4(t1, np_[1]) + dot4(t2, np_[2]) + dot4(t3, np_[3]);
        }

        // butterfly reduce within the 8-lane group: 3 steps x 6 values
        #pragma unroll
        for (int m = 4; m >= 1; m >>= 1) {
            dp += __shfl_xor(dp, m, 64);
            #pragma unroll
            for (int j = 0; j < NEG; ++j) dn[j] += __shfl_xor(dn[j], m, 64);
        }

        // all 8 lanes hold the full sums; accumulate on ALL lanes (8x redundant,
        // divided out in finalize) -- same instruction count, no divergence.
        pos_acc += softplus_fast(-dp);   // -log_sigmoid(dp)
        float s = 0.0f;
        #pragma unroll
        for (int j = 0; j < NEG; ++j) s += softplus_fast(dn[j]);  // -log_sigmoid(-dn)
        neg_acc += s;
    }

    // block reduction over 256 threads
    __shared__ float sp[256];
    __shared__ float sn[256];
    sp[tid] = pos_acc;
    sn[tid] = neg_acc;
    __syncthreads();
    #pragma unroll
    for (int s = 128; s > 0; s >>= 1) {
        if (tid < s) {
            sp[tid] += sp[tid + s];
            sn[tid] += sn[tid + s];
        }
        __syncthreads();
    }
    if (tid == 0) {
        atomicAdd(&acc[0], sp[0]);
        atomicAdd(&acc[1], sn[0]);
    }
}

__global__ void ns_finalize_kernel(const float* __restrict__ acc, float* __restrict__ out) {
    // each element's losses were accumulated by all 8 lanes of its group
    out[0] = acc[0] * (1.0f / ((float)BATCH * 8.0f));
    out[1] = acc[1] * (1.0f / ((float)BATCH * (float)NEG * 8.0f));
}

extern "C" void kernel_launch(void* const* d_in, const int* in_sizes, int n_in,
                              void* d_out, int out_size, void* d_ws, size_t ws_size,
                              hipStream_t stream) {
    const int*   tgt  = (const int*)d_in[0];
    const int*   ctx  = (const int*)d_in[1];
    const int*   negw = (const int*)d_in[2];
    const float* iemb = (const float*)d_in[3];
    const float* oemb = (const float*)d_in[4];
    float* out = (float*)d_out;
    float* acc = (float*)d_ws;

    ns_init_kernel<<<1, 1, 0, stream>>>(acc);
    ns_loss_kernel<<<2048, 256, 0, stream>>>(tgt, ctx, negw, iemb, oemb, acc);
    ns_finalize_kernel<<<1, 1, 0, stream>>>(acc, out);
}